// Round 3
// baseline (6954.454 us; speedup 1.0000x reference)
//
#include <hip/hip_runtime.h>

typedef __bf16   bf16x8 __attribute__((ext_vector_type(8)));
typedef float    f32x4  __attribute__((ext_vector_type(4)));
typedef unsigned int u32x4 __attribute__((ext_vector_type(4)));
typedef _Float16 f16_t;

#define NB 64
#define NS 512
#define NI 768
#define NH 512

// ---------------- workspace layout (bytes), total ~276.6 MB ----------------
// wiT_h: bf16 [2][2048][768]      @ 0           ( 6,291,456)
// wiT_l: bf16 [2][2048][768]      @ 6291456     ( 6,291,456)
// whT_h: bf16 [2][2048][512]      @ 12582912    ( 4,194,304)
// whT_l: bf16 [2][2048][512]      @ 16777216    ( 4,194,304)
// xp   : f16  [2][32][512][64][64] @ 20971520   (268,435,456)  (dir,jb,t,b,g*16+jj)
//        NOTE: after the recurrence consumes page (dir,jb,t), its first 4 KB is
//        overwritten with the WG's packed h history (hist) for expand_out.
// hpk  : u32  [2dir][2par][64 chunks][512] @ 289406976 (524,288)
//        chunk c = w*16 + mi*4 + kb holds A-frag (b=mi*16+jj, k=w*128+kb*32+q*8+j)
//        u32 idx in chunk = (j>>1)*128 + (q*16+jj)*2 + (j&1)   (hi<<16|lo packed)
// flags: u32  [2dir][32]          @ 289931264   (256)   flag[jb] = last published step + 1
#define WS_WITH  0L
#define WS_WITL  6291456L
#define WS_WHTH  12582912L
#define WS_WHTL  16777216L
#define WS_XP    20971520L
#define WS_HPK   289406976L
#define WS_CNT   289931264L

__device__ __forceinline__ float fsig(float x) {
  return __builtin_amdgcn_rcpf(1.f + __builtin_amdgcn_exp2f(-1.442695040888963f * x));
}
__device__ __forceinline__ float ftanh(float x) {
  return 1.f - 2.f * __builtin_amdgcn_rcpf(1.f + __builtin_amdgcn_exp2f(2.885390081777926f * x));
}

// split 8 consecutive LDS floats into hi/lo bf16x8 fragments
__device__ __forceinline__ void split8(const float* p, bf16x8& hi, bf16x8& lo) {
#pragma unroll
  for (int j = 0; j < 8; ++j) {
    float v = p[j];
    __bf16 h = (__bf16)v;
    hi[j] = h;
    lo[j] = (__bf16)(v - (float)h);
  }
}

// Chunked A-fragment load: p = chunk_base_u64 + lane. The 4 u64 loads have
// 8 B lane stride (fully coalesced, 512 B dense per instruction). u64 s holds
// packed u32 pair (j=2s, j=2s+1); unpack hi/lo bf16x8 with v_perm.
__device__ __forceinline__ void loadA16c(const unsigned long long* p, bf16x8& hi, bf16x8& lo) {
  unsigned long long q0 = __hip_atomic_load(p +   0, __ATOMIC_RELAXED, __HIP_MEMORY_SCOPE_AGENT);
  unsigned long long q1 = __hip_atomic_load(p +  64, __ATOMIC_RELAXED, __HIP_MEMORY_SCOPE_AGENT);
  unsigned long long q2 = __hip_atomic_load(p + 128, __ATOMIC_RELAXED, __HIP_MEMORY_SCOPE_AGENT);
  unsigned long long q3 = __hip_atomic_load(p + 192, __ATOMIC_RELAXED, __HIP_MEMORY_SCOPE_AGENT);
  unsigned a0 = (unsigned)q0, a1 = (unsigned)(q0 >> 32);
  unsigned a2 = (unsigned)q1, a3 = (unsigned)(q1 >> 32);
  unsigned a4 = (unsigned)q2, a5 = (unsigned)(q2 >> 32);
  unsigned a6 = (unsigned)q3, a7 = (unsigned)(q3 >> 32);
  union { unsigned u[4]; bf16x8 v; } H, L;
  H.u[0] = __builtin_amdgcn_perm(a1, a0, 0x07060302);
  H.u[1] = __builtin_amdgcn_perm(a3, a2, 0x07060302);
  H.u[2] = __builtin_amdgcn_perm(a5, a4, 0x07060302);
  H.u[3] = __builtin_amdgcn_perm(a7, a6, 0x07060302);
  L.u[0] = __builtin_amdgcn_perm(a1, a0, 0x05040100);
  L.u[1] = __builtin_amdgcn_perm(a3, a2, 0x05040100);
  L.u[2] = __builtin_amdgcn_perm(a5, a4, 0x05040100);
  L.u[3] = __builtin_amdgcn_perm(a7, a6, 0x05040100);
  hi = H.v; lo = L.v;
}

// ---------------- prep: zero hpk + flags ----------------
__global__ __launch_bounds__(256) void prep_zero(unsigned int* __restrict__ zr) {
  unsigned wi = blockIdx.x * 256u + threadIdx.x;
  if (wi < 132096u) zr[wi] = 0u;  // hpk (131072 words) + flags (64 words) + pad
}

// ---------------- prep: transpose + split-cast Wi/Wh -> [N][K] bf16 hi+lo ----------------
__global__ __launch_bounds__(256) void transpose_cast(
    const float* __restrict__ Wi_f, const float* __restrict__ Wh_f,
    const float* __restrict__ Wi_b, const float* __restrict__ Wh_b,
    __bf16* __restrict__ wiT_h, __bf16* __restrict__ wiT_l,
    __bf16* __restrict__ whT_h, __bf16* __restrict__ whT_l)
{
  int mat = blockIdx.y;  // 0:Wi_f 1:Wh_f 2:Wi_b 3:Wh_b
  const float* src = (mat == 0) ? Wi_f : (mat == 1) ? Wh_f : (mat == 2) ? Wi_b : Wh_b;
  int K = (mat & 1) ? NH : NI;
  size_t doff = (mat >= 2) ? (size_t)2048 * K : 0;
  __bf16* dh = ((mat & 1) ? whT_h : wiT_h) + doff;
  __bf16* dl = ((mat & 1) ? whT_l : wiT_l) + doff;
  int ntk = K / 32;
  int t = blockIdx.x;
  if (t >= ntk * 64) return;
  int tk = t >> 6, tn = t & 63;
  __shared__ float tb[32][33];
  int tx = threadIdx.x & 31, ty = threadIdx.x >> 5;
#pragma unroll
  for (int i = 0; i < 4; ++i)
    tb[ty + i * 8][tx] = src[(size_t)(tk * 32 + ty + i * 8) * 2048 + tn * 32 + tx];
  __syncthreads();
#pragma unroll
  for (int i = 0; i < 4; ++i) {
    float v = tb[tx][ty + i * 8];
    __bf16 hi = (__bf16)v;
    size_t o = (size_t)(tn * 32 + ty + i * 8) * K + tk * 32 + tx;
    dh[o] = hi;
    dl[o] = (__bf16)(v - (float)hi);
  }
}

// ---------------- phase 1: xp = x @ Wi + (bi + bh), f16 out, 3-term split ----------------
// Output in recurrence-friendly layout: xp[dir][jb][t][b][g*16+jj].
__global__ __launch_bounds__(256) void gemm_xproj(
    const float* __restrict__ x,
    const __bf16* __restrict__ wih, const __bf16* __restrict__ wil,
    const float* __restrict__ bi_f, const float* __restrict__ bh_f,
    const float* __restrict__ bi_b, const float* __restrict__ bh_b,
    f16_t* __restrict__ xp)
{
  int dir = blockIdx.y;
  int tm = blockIdx.x >> 4, tn = blockIdx.x & 15;
  const float*  Af = x + (size_t)tm * 128 * NI;
  const __bf16* Bh = wih + (size_t)dir * 2048 * NI + (size_t)tn * 128 * NI;
  const __bf16* Bl = wil + (size_t)dir * 2048 * NI + (size_t)tn * 128 * NI;
  const float* bi = dir ? bi_b : bi_f;
  const float* bh = dir ? bh_b : bh_f;

  __shared__ float  sA[128 * 32];
  __shared__ __bf16 sBh[128 * 32];
  __shared__ __bf16 sBl[128 * 32];
  int tid = threadIdx.x, w = tid >> 6, lane = tid & 63;
  int wm = w >> 1, wn = w & 1;
  int q = lane >> 4, m16 = lane & 15;

  f32x4 acc[4][4] = {};
  for (int kb = 0; kb < NI / 32; ++kb) {
#pragma unroll
    for (int i = 0; i < 4; ++i) {
      int ch = tid + i * 256;
      int r = ch >> 3, c = ch & 7;
      __builtin_amdgcn_global_load_lds(
          (__attribute__((address_space(1))) void*)(Af + (size_t)r * NI + kb * 32 + c * 4),
          (__attribute__((address_space(3))) void*)(sA + ch * 4), 16, 0, 0);
    }
#pragma unroll
    for (int i = 0; i < 2; ++i) {
      int ch = tid + i * 256;
      int r = ch >> 2, c = ch & 3;
      size_t go = (size_t)r * NI + kb * 32 + c * 8;
      __builtin_amdgcn_global_load_lds(
          (__attribute__((address_space(1))) void*)(Bh + go),
          (__attribute__((address_space(3))) void*)(sBh + ch * 8), 16, 0, 0);
      __builtin_amdgcn_global_load_lds(
          (__attribute__((address_space(1))) void*)(Bl + go),
          (__attribute__((address_space(3))) void*)(sBl + ch * 8), 16, 0, 0);
    }
    __syncthreads();
    bf16x8 afh[4], afl[4], bfh[4], bfl[4];
#pragma unroll
    for (int i = 0; i < 4; ++i) {
      split8(sA + (wm * 64 + i * 16 + m16) * 32 + q * 8, afh[i], afl[i]);
      int bo = (wn * 64 + i * 16 + m16) * 32 + q * 8;
      bfh[i] = *(const bf16x8*)(sBh + bo);
      bfl[i] = *(const bf16x8*)(sBl + bo);
    }
#pragma unroll
    for (int mi = 0; mi < 4; ++mi)
#pragma unroll
      for (int ni = 0; ni < 4; ++ni) {
        acc[mi][ni] = __builtin_amdgcn_mfma_f32_16x16x32_bf16(afh[mi], bfh[ni], acc[mi][ni], 0, 0, 0);
        acc[mi][ni] = __builtin_amdgcn_mfma_f32_16x16x32_bf16(afl[mi], bfh[ni], acc[mi][ni], 0, 0, 0);
        acc[mi][ni] = __builtin_amdgcn_mfma_f32_16x16x32_bf16(afh[mi], bfl[ni], acc[mi][ni], 0, 0, 0);
      }
    __syncthreads();
  }
#pragma unroll
  for (int ni = 0; ni < 4; ++ni) {
    int n = tn * 128 + wn * 64 + ni * 16 + m16;
    int g = n >> 9, jbx = (n >> 4) & 31, jjx = n & 15;
    float bias = bi[n] + bh[n];
    size_t nbase = ((size_t)(dir * 32 + jbx) * 512) * 4096 + g * 16 + jjx;
#pragma unroll
    for (int mi = 0; mi < 4; ++mi) {
#pragma unroll
      for (int r = 0; r < 4; ++r) {
        int m = tm * 128 + wm * 64 + mi * 16 + q * 4 + r;
        int b = m >> 9, t = m & 511;
        xp[nbase + (size_t)t * 4096 + b * 64] = (f16_t)(acc[mi][ni][r] + bias);
      }
    }
  }
}

// ---------------- phase 2: recurrence, fine-grained flag handshake ----------------
// 64 WGs (32/dir), 256 threads, 1 WG/CU. WG (dir,jb) owns h cols [16jb,16jb+16).
// Wave w owns k-slice [128w,128w+128); its 16 chunks are produced by exactly
// the 8 WGs jb in [8w, 8w+8).  Handshake = per-WG flag line (flag[jb] =
// published step + 1):
//   - top of step: each wave polls only ITS 8 producers, then proceeds to
//     loads+MFMA immediately (no WG barrier; straggler tail overlaps compute)
//   - pre-publish: all waves poll all-32 flags >= step (write-safety for the
//     parity buffer about to be overwritten) -- after MFMA, usually free
//   - tid0 stores flag = step+1 after the drain barrier
// out[] is NOT written here: the publish u32x4 is also stored densely into the
// just-consumed xp page (4 KB/WG/step); expand_out inverts it afterward.
__global__ __launch_bounds__(256, 1) void lstm_recur(
    f16_t* xp, const __bf16* __restrict__ whh,
    const __bf16* __restrict__ whl, const float* __restrict__ sent,
    unsigned int* __restrict__ hpk, unsigned int* __restrict__ flags)
{
  int dir = blockIdx.x >> 5;
  int jb  = blockIdx.x & 31;
  int tid = threadIdx.x, w = tid >> 6, lane = tid & 63;
  int q = lane >> 4, jj = lane & 15;
  const int cbase = ((jb >> 3) << 4) + ((jb >> 1) & 3);  // chunk base for this WG's cols

  // B fragments (step-invariant) -> registers. [g][kb], k = w*128+kb*32+q*8+i.
  bf16x8 bh_r[4][4], bl_r[4][4];
  {
    const __bf16* sh = whh + (size_t)dir * 2048 * NH;
    const __bf16* sl = whl + (size_t)dir * 2048 * NH;
#pragma unroll
    for (int g = 0; g < 4; ++g) {
      size_t nrow = (size_t)(g * NH + jb * 16 + jj) * NH + w * 128 + q * 8;
#pragma unroll
      for (int kb = 0; kb < 4; ++kb) {
        bh_r[g][kb] = *(const bf16x8*)(sh + nrow + kb * 32);
        bl_r[g][kb] = *(const bf16x8*)(sl + nrow + kb * 32);
      }
    }
  }

  __shared__ f32x4 pbuf[4][4][4][64];           // [src_wave][mi][g][lane], 64 KB
  __shared__ unsigned int stage[4][4][2][32];   // [w][s][jj>>3][(b&15)*2+par], 4 KB

  float cst[4] = {0.f, 0.f, 0.f, 0.f};
  unsigned int* fl = flags + dir * 32;
  f16_t* xslab = xp + ((size_t)(dir * 32 + jb) * 512) * 4096;

  for (int step = 0; step < NS; ++step) {
    int t = dir ? (NS - 1 - step) : step;

    // xp + sentiment prefetch (independent of h -> overlaps the wait)
    float xg[4][4];  // [g][r]
    float st[4];
    {
      const f16_t* xrow = xslab + (size_t)t * 4096;
#pragma unroll
      for (int r = 0; r < 4; ++r) {
        int b = w * 16 + q * 4 + r;
#pragma unroll
        for (int g = 0; g < 4; ++g)
          xg[g][r] = (float)xrow[b * 64 + g * 16 + jj];
        st[r] = sent[b * NS + t];
      }
    }

    // data-ready wait: wave w needs only its 8 producers (jb in [8w,8w+8))
    if (step) {
      unsigned v = 0;
      for (;;) {
        if (lane < 8)
          v = __hip_atomic_load(fl + w * 8 + lane, __ATOMIC_RELAXED, __HIP_MEMORY_SCOPE_AGENT);
        if (__all(lane >= 8 || v >= (unsigned)step)) break;
        __builtin_amdgcn_s_sleep(1);
      }
    }

    const unsigned long long* hrd =
        (const unsigned long long*)(hpk + (size_t)(dir * 2 + (step & 1)) * 32768);
    unsigned int* hwr = hpk + (size_t)(dir * 2 + ((step & 1) ^ 1)) * 32768;

    f32x4 acc[4][4] = {};  // [mi][g] k-partials for this wave's slice
    if (step) {
      bf16x8 Ah[2][4], Al[2][4];
      const unsigned long long* hb = hrd + ((size_t)w << 12) + lane;  // wave's 16 chunks
#pragma unroll
      for (int kb = 0; kb < 4; ++kb)
        loadA16c(hb + kb * 256, Ah[0][kb], Al[0][kb]);
#pragma unroll
      for (int mi = 0; mi < 4; ++mi) {
        int cur = mi & 1;
        if (mi < 3) {
#pragma unroll
          for (int kb = 0; kb < 4; ++kb)
            loadA16c(hb + ((mi + 1) * 4 + kb) * 256, Ah[cur ^ 1][kb], Al[cur ^ 1][kb]);
        }
#pragma unroll
        for (int kb = 0; kb < 4; ++kb)
#pragma unroll
          for (int g = 0; g < 4; ++g) {
            acc[mi][g] = __builtin_amdgcn_mfma_f32_16x16x32_bf16(Ah[cur][kb], bh_r[g][kb], acc[mi][g], 0, 0, 0);
            acc[mi][g] = __builtin_amdgcn_mfma_f32_16x16x32_bf16(Al[cur][kb], bh_r[g][kb], acc[mi][g], 0, 0, 0);
            acc[mi][g] = __builtin_amdgcn_mfma_f32_16x16x32_bf16(Ah[cur][kb], bl_r[g][kb], acc[mi][g], 0, 0, 0);
          }
      }
    }

    // cross-wave k-reduction through LDS (lane-indexed b128, conflict-free)
#pragma unroll
    for (int mi = 0; mi < 4; ++mi)
      if (mi != w)
#pragma unroll
        for (int g = 0; g < 4; ++g) pbuf[w][mi][g][lane] = acc[mi][g];
    __syncthreads();
    f32x4 gates[4];
#pragma unroll
    for (int g = 0; g < 4; ++g) gates[g] = acc[w][g];
#pragma unroll
    for (int w2 = 0; w2 < 4; ++w2)
      if (w2 != w)
#pragma unroll
        for (int g = 0; g < 4; ++g) gates[g] += pbuf[w2][w][g][lane];

    // elementwise: lane owns (b = w*16+q*4+r, jj); h goes to LDS stage
#pragma unroll
    for (int r = 0; r < 4; ++r) {
      int b = w * 16 + q * 4 + r;
      float it = fsig(gates[0][r] + xg[0][r]) * st[r];
      float ft = fsig(gates[1][r] + xg[1][r]) * (1.f + st[r]);
      float gt = ftanh(gates[2][r] + xg[2][r]);
      float ot = fsig(gates[3][r] + xg[3][r]);
      float cv = ft * cst[r] + it * gt;
      cst[r] = cv;
      float h = ot * ftanh(cv);
      __bf16 h_hi = (__bf16)h;
      __bf16 h_lo = (__bf16)(h - (float)h_hi);
      unsigned pk = ((unsigned)__builtin_bit_cast(unsigned short, h_hi) << 16)
                  | (unsigned)__builtin_bit_cast(unsigned short, h_lo);
      stage[w][(jj >> 1) & 3][jj >> 3][((q * 4 + r) << 1) + (jj & 1)] = pk;
    }

    // write-safety wait: everyone published step-1 => the parity buffer we are
    // about to overwrite has been fully consumed. Runs after MFMA: usually free.
    if (step) {
      unsigned v = 0;
      for (;;) {
        if (lane < 32)
          v = __hip_atomic_load(fl + lane, __ATOMIC_RELAXED, __HIP_MEMORY_SCOPE_AGENT);
        if (__all(lane >= 32 || v >= (unsigned)step)) break;
        __builtin_amdgcn_s_sleep(1);
      }
    }
    __syncthreads();

    // publish: 256 threads x 1 dwordx4 store (each wave instr = 1024 B dense,
    // full-line write-through) + dense hist copy into the consumed xp page
    {
      int rid  = tid >> 3;        // 0..31
      int wp   = rid >> 3;        // chunk mi = producer wave
      int s    = (rid >> 1) & 3;  // u64 slot
      int hi3  = rid & 1;         // jj>>3 half
      int slot = tid & 7;         // 16 B within the 128 B run
      const unsigned int* sp = &stage[wp][s][hi3][slot << 2];
      unsigned base = ((unsigned)(cbase + (wp << 2)) << 9) + ((unsigned)s << 7)
                    + ((unsigned)((jb * 2 + hi3) & 3) << 5) + ((unsigned)slot << 2);
      u32x4 v;
      v.x = sp[0]; v.y = sp[1]; v.z = sp[2]; v.w = sp[3];
      asm volatile("global_store_dwordx4 %0, %1, off sc0 sc1"
                   :: "v"((unsigned long long)(hwr + base)), "v"(v) : "memory");
      // hist: same values, dense 4 KB into the first half of this step's xp page
      unsigned int* histpg = (unsigned int*)(xslab + (size_t)t * 4096);
      *(u32x4*)(histpg + (tid << 2)) = v;
    }

    // barrier drains vmcnt(0): publishes are at the coherent point; then flag.
    __syncthreads();
    if (tid == 0)
      __hip_atomic_store(fl + jb, (unsigned)(step + 1),
                         __ATOMIC_RELAXED, __HIP_MEMORY_SCOPE_AGENT);
  }
}

// ---------------- phase 3: expand packed h history -> out [B,S,2H] f32 ----------------
// hist page (dir,jb,t) at u32 offset ((dir*32+jb)*512 + t)*2048, first 1024 used.
// Forward map (publish): histpg[tid*4+e] holds pk for
//   wp=tid>>6, s=(tid>>4)&3, hi3=(tid>>3)&1, slot=tid&7, idx=slot*4+e,
//   b = wp*16 + (idx>>1), jj = hi3*8 + s*2 + (idx&1).
__global__ __launch_bounds__(256) void expand_out(
    const unsigned int* __restrict__ hist, float* __restrict__ out)
{
  int t   = blockIdx.x;                    // 512
  int dj  = blockIdx.y * 4 + (threadIdx.x & 3);  // (dir,jb) pair
  int b   = threadIdx.x >> 2;              // 64
  int dir = dj >> 5, jb = dj & 31;
  const unsigned int* pg = hist + ((size_t)(dir * 32 + jb) * 512 + t) * 2048;
  int wp = b >> 4, bl = b & 15;
  float vals[16];
#pragma unroll
  for (int jj = 0; jj < 16; ++jj) {
    int idx  = (bl << 1) | (jj & 1);
    int slot = idx >> 2, e = idx & 3;
    int hi3  = jj >> 3, s = (jj >> 1) & 3;
    int p    = (((wp << 6) | (s << 4) | (hi3 << 3) | slot) << 2) + e;
    unsigned pk = pg[p];
    float hi = (float)__builtin_bit_cast(__bf16, (unsigned short)(pk >> 16));
    float lo = (float)__builtin_bit_cast(__bf16, (unsigned short)(pk & 0xffffu));
    vals[jj] = hi + lo;
  }
  float* dst = out + ((size_t)b * NS + t) * 1024 + dir * 512 + jb * 16;
#pragma unroll
  for (int k = 0; k < 4; ++k) {
    f32x4 v;
    v[0] = vals[k * 4]; v[1] = vals[k * 4 + 1];
    v[2] = vals[k * 4 + 2]; v[3] = vals[k * 4 + 3];
    *(f32x4*)(dst + k * 4) = v;
  }
}

extern "C" void kernel_launch(void* const* d_in, const int* in_sizes, int n_in,
                              void* d_out, int out_size, void* d_ws, size_t ws_size,
                              hipStream_t stream) {
  const float* x    = (const float*)d_in[0];
  const float* sent = (const float*)d_in[1];
  const float* Wi_f = (const float*)d_in[2];
  const float* bi_f = (const float*)d_in[3];
  const float* Wh_f = (const float*)d_in[4];
  const float* bh_f = (const float*)d_in[5];
  const float* Wi_b = (const float*)d_in[6];
  const float* bi_b = (const float*)d_in[7];
  const float* Wh_b = (const float*)d_in[8];
  const float* bh_b = (const float*)d_in[9];

  char* ws = (char*)d_ws;
  __bf16*       wiT_h = (__bf16*)(ws + WS_WITH);
  __bf16*       wiT_l = (__bf16*)(ws + WS_WITL);
  __bf16*       whT_h = (__bf16*)(ws + WS_WHTH);
  __bf16*       whT_l = (__bf16*)(ws + WS_WHTL);
  f16_t*        xp    = (f16_t*)(ws + WS_XP);
  unsigned int* hpk   = (unsigned int*)(ws + WS_HPK);
  unsigned int* flags = (unsigned int*)(ws + WS_CNT);
  unsigned int* zr    = (unsigned int*)(ws + WS_HPK);  // hpk+flags contiguous

  prep_zero<<<dim3(517), dim3(256), 0, stream>>>(zr);
  transpose_cast<<<dim3(1536, 4), dim3(256), 0, stream>>>(
      Wi_f, Wh_f, Wi_b, Wh_b, wiT_h, wiT_l, whT_h, whT_l);
  gemm_xproj<<<dim3(4096, 2), dim3(256), 0, stream>>>(
      x, wiT_h, wiT_l, bi_f, bh_f, bi_b, bh_b, xp);
  lstm_recur<<<dim3(64), dim3(256), 0, stream>>>(
      xp, whT_h, whT_l, sent, hpk, flags);
  expand_out<<<dim3(512, 16), dim3(256), 0, stream>>>(
      (const unsigned int*)xp, (float*)d_out);
}

// Round 4
// 5070.438 us; speedup vs baseline: 1.3716x; 1.3716x over previous
//
#include <hip/hip_runtime.h>

typedef __bf16   bf16x8 __attribute__((ext_vector_type(8)));
typedef float    f32x4  __attribute__((ext_vector_type(4)));
typedef unsigned int u32x4 __attribute__((ext_vector_type(4)));
typedef _Float16 f16_t;

#define NB 64
#define NS 512
#define NI 768
#define NH 512

// ---------------- workspace layout (bytes), total ~276.6 MB ----------------
// wiT_h: bf16 [2][2048][768]      @ 0           ( 6,291,456)
// wiT_l: bf16 [2][2048][768]      @ 6291456     ( 6,291,456)
// whT_h: bf16 [2][2048][512]      @ 12582912    ( 4,194,304)
// whT_l: bf16 [2][2048][512]      @ 16777216    ( 4,194,304)
// xp   : f16  [2][32][512][64][64] @ 20971520   (268,435,456)  (dir,jb,t,b,g*16+jj)
// hpk  : u32  [2dir][2par][64 chunks][512] @ 289406976 (524,288)
//        chunk c = w*16 + mi*4 + kb holds A-frag (b=mi*16+jj, k=w*128+kb*32+q*8+j)
//        u32 idx in chunk = (j>>1)*128 + (q*16+jj)*2 + (j&1)   (hi<<16|lo packed)
//        batch-split: chunks mi in {0,1} belong to half hb=0, {2,3} to hb=1.
// flags: u32  [2dir][2hb][32]     @ 289931264   (512)  flag[jb] = published step+1
//        each 32-flag group is one 128 B line; 4 independent handshake systems.
#define WS_WITH  0L
#define WS_WITL  6291456L
#define WS_WHTH  12582912L
#define WS_WHTL  16777216L
#define WS_XP    20971520L
#define WS_HPK   289406976L
#define WS_CNT   289931264L

__device__ __forceinline__ float fsig(float x) {
  return __builtin_amdgcn_rcpf(1.f + __builtin_amdgcn_exp2f(-1.442695040888963f * x));
}
__device__ __forceinline__ float ftanh(float x) {
  return 1.f - 2.f * __builtin_amdgcn_rcpf(1.f + __builtin_amdgcn_exp2f(2.885390081777926f * x));
}

// split 8 consecutive LDS floats into hi/lo bf16x8 fragments
__device__ __forceinline__ void split8(const float* p, bf16x8& hi, bf16x8& lo) {
#pragma unroll
  for (int j = 0; j < 8; ++j) {
    float v = p[j];
    __bf16 h = (__bf16)v;
    hi[j] = h;
    lo[j] = (__bf16)(v - (float)h);
  }
}

// Chunked A-fragment load: p = chunk_base_u64 + lane. The 4 u64 loads have
// 8 B lane stride (fully coalesced, 512 B dense per instruction). u64 s holds
// packed u32 pair (j=2s, j=2s+1); unpack hi/lo bf16x8 with v_perm.
__device__ __forceinline__ void loadA16c(const unsigned long long* p, bf16x8& hi, bf16x8& lo) {
  unsigned long long q0 = __hip_atomic_load(p +   0, __ATOMIC_RELAXED, __HIP_MEMORY_SCOPE_AGENT);
  unsigned long long q1 = __hip_atomic_load(p +  64, __ATOMIC_RELAXED, __HIP_MEMORY_SCOPE_AGENT);
  unsigned long long q2 = __hip_atomic_load(p + 128, __ATOMIC_RELAXED, __HIP_MEMORY_SCOPE_AGENT);
  unsigned long long q3 = __hip_atomic_load(p + 192, __ATOMIC_RELAXED, __HIP_MEMORY_SCOPE_AGENT);
  unsigned a0 = (unsigned)q0, a1 = (unsigned)(q0 >> 32);
  unsigned a2 = (unsigned)q1, a3 = (unsigned)(q1 >> 32);
  unsigned a4 = (unsigned)q2, a5 = (unsigned)(q2 >> 32);
  unsigned a6 = (unsigned)q3, a7 = (unsigned)(q3 >> 32);
  union { unsigned u[4]; bf16x8 v; } H, L;
  H.u[0] = __builtin_amdgcn_perm(a1, a0, 0x07060302);
  H.u[1] = __builtin_amdgcn_perm(a3, a2, 0x07060302);
  H.u[2] = __builtin_amdgcn_perm(a5, a4, 0x07060302);
  H.u[3] = __builtin_amdgcn_perm(a7, a6, 0x07060302);
  L.u[0] = __builtin_amdgcn_perm(a1, a0, 0x05040100);
  L.u[1] = __builtin_amdgcn_perm(a3, a2, 0x05040100);
  L.u[2] = __builtin_amdgcn_perm(a5, a4, 0x05040100);
  L.u[3] = __builtin_amdgcn_perm(a7, a6, 0x05040100);
  hi = H.v; lo = L.v;
}

// ---------------- prep: zero hpk + flags ----------------
__global__ __launch_bounds__(256) void prep_zero(unsigned int* __restrict__ zr) {
  unsigned wi = blockIdx.x * 256u + threadIdx.x;
  if (wi < 131200u) zr[wi] = 0u;  // hpk (131072 words) + flags (128 words)
}

// ---------------- prep: transpose + split-cast Wi/Wh -> [N][K] bf16 hi+lo ----------------
__global__ __launch_bounds__(256) void transpose_cast(
    const float* __restrict__ Wi_f, const float* __restrict__ Wh_f,
    const float* __restrict__ Wi_b, const float* __restrict__ Wh_b,
    __bf16* __restrict__ wiT_h, __bf16* __restrict__ wiT_l,
    __bf16* __restrict__ whT_h, __bf16* __restrict__ whT_l)
{
  int mat = blockIdx.y;  // 0:Wi_f 1:Wh_f 2:Wi_b 3:Wh_b
  const float* src = (mat == 0) ? Wi_f : (mat == 1) ? Wh_f : (mat == 2) ? Wi_b : Wh_b;
  int K = (mat & 1) ? NH : NI;
  size_t doff = (mat >= 2) ? (size_t)2048 * K : 0;
  __bf16* dh = ((mat & 1) ? whT_h : wiT_h) + doff;
  __bf16* dl = ((mat & 1) ? whT_l : wiT_l) + doff;
  int ntk = K / 32;
  int t = blockIdx.x;
  if (t >= ntk * 64) return;
  int tk = t >> 6, tn = t & 63;
  __shared__ float tb[32][33];
  int tx = threadIdx.x & 31, ty = threadIdx.x >> 5;
#pragma unroll
  for (int i = 0; i < 4; ++i)
    tb[ty + i * 8][tx] = src[(size_t)(tk * 32 + ty + i * 8) * 2048 + tn * 32 + tx];
  __syncthreads();
#pragma unroll
  for (int i = 0; i < 4; ++i) {
    float v = tb[tx][ty + i * 8];
    __bf16 hi = (__bf16)v;
    size_t o = (size_t)(tn * 32 + ty + i * 8) * K + tk * 32 + tx;
    dh[o] = hi;
    dl[o] = (__bf16)(v - (float)hi);
  }
}

// ---------------- phase 1: xp = x @ Wi + (bi + bh), f16 out, 3-term split ----------------
// Output in recurrence-friendly layout: xp[dir][jb][t][b][g*16+jj].
__global__ __launch_bounds__(256) void gemm_xproj(
    const float* __restrict__ x,
    const __bf16* __restrict__ wih, const __bf16* __restrict__ wil,
    const float* __restrict__ bi_f, const float* __restrict__ bh_f,
    const float* __restrict__ bi_b, const float* __restrict__ bh_b,
    f16_t* __restrict__ xp)
{
  int dir = blockIdx.y;
  int tm = blockIdx.x >> 4, tn = blockIdx.x & 15;
  const float*  Af = x + (size_t)tm * 128 * NI;
  const __bf16* Bh = wih + (size_t)dir * 2048 * NI + (size_t)tn * 128 * NI;
  const __bf16* Bl = wil + (size_t)dir * 2048 * NI + (size_t)tn * 128 * NI;
  const float* bi = dir ? bi_b : bi_f;
  const float* bh = dir ? bh_b : bh_f;

  __shared__ float  sA[128 * 32];
  __shared__ __bf16 sBh[128 * 32];
  __shared__ __bf16 sBl[128 * 32];
  int tid = threadIdx.x, w = tid >> 6, lane = tid & 63;
  int wm = w >> 1, wn = w & 1;
  int q = lane >> 4, m16 = lane & 15;

  f32x4 acc[4][4] = {};
  for (int kb = 0; kb < NI / 32; ++kb) {
#pragma unroll
    for (int i = 0; i < 4; ++i) {
      int ch = tid + i * 256;
      int r = ch >> 3, c = ch & 7;
      __builtin_amdgcn_global_load_lds(
          (__attribute__((address_space(1))) void*)(Af + (size_t)r * NI + kb * 32 + c * 4),
          (__attribute__((address_space(3))) void*)(sA + ch * 4), 16, 0, 0);
    }
#pragma unroll
    for (int i = 0; i < 2; ++i) {
      int ch = tid + i * 256;
      int r = ch >> 2, c = ch & 3;
      size_t go = (size_t)r * NI + kb * 32 + c * 8;
      __builtin_amdgcn_global_load_lds(
          (__attribute__((address_space(1))) void*)(Bh + go),
          (__attribute__((address_space(3))) void*)(sBh + ch * 8), 16, 0, 0);
      __builtin_amdgcn_global_load_lds(
          (__attribute__((address_space(1))) void*)(Bl + go),
          (__attribute__((address_space(3))) void*)(sBl + ch * 8), 16, 0, 0);
    }
    __syncthreads();
    bf16x8 afh[4], afl[4], bfh[4], bfl[4];
#pragma unroll
    for (int i = 0; i < 4; ++i) {
      split8(sA + (wm * 64 + i * 16 + m16) * 32 + q * 8, afh[i], afl[i]);
      int bo = (wn * 64 + i * 16 + m16) * 32 + q * 8;
      bfh[i] = *(const bf16x8*)(sBh + bo);
      bfl[i] = *(const bf16x8*)(sBl + bo);
    }
#pragma unroll
    for (int mi = 0; mi < 4; ++mi)
#pragma unroll
      for (int ni = 0; ni < 4; ++ni) {
        acc[mi][ni] = __builtin_amdgcn_mfma_f32_16x16x32_bf16(afh[mi], bfh[ni], acc[mi][ni], 0, 0, 0);
        acc[mi][ni] = __builtin_amdgcn_mfma_f32_16x16x32_bf16(afl[mi], bfh[ni], acc[mi][ni], 0, 0, 0);
        acc[mi][ni] = __builtin_amdgcn_mfma_f32_16x16x32_bf16(afh[mi], bfl[ni], acc[mi][ni], 0, 0, 0);
      }
    __syncthreads();
  }
#pragma unroll
  for (int ni = 0; ni < 4; ++ni) {
    int n = tn * 128 + wn * 64 + ni * 16 + m16;
    int g = n >> 9, jbx = (n >> 4) & 31, jjx = n & 15;
    float bias = bi[n] + bh[n];
    size_t nbase = ((size_t)(dir * 32 + jbx) * 512) * 4096 + g * 16 + jjx;
#pragma unroll
    for (int mi = 0; mi < 4; ++mi) {
#pragma unroll
      for (int r = 0; r < 4; ++r) {
        int m = tm * 128 + wm * 64 + mi * 16 + q * 4 + r;
        int b = m >> 9, t = m & 511;
        xp[nbase + (size_t)t * 4096 + b * 64] = (f16_t)(acc[mi][ni][r] + bias);
      }
    }
  }
}

// ---------------- phase 2: recurrence, batch-split 2x ----------------
// 128 WGs (2 dir x 2 batch-half x 32 jb), 256 threads, 1 WG/CU target.
// WG (dir,hb,jb) owns h cols [16jb,16jb+16) for batches [32hb, 32hb+32)
// (b-groups mi in {2hb, 2hb+1}). Chunk map: mi {0,1} <-> hb 0, {2,3} <-> hb 1,
// so each (dir,hb) is an INDEPENDENT 32-WG exchange system with its own
// 1-line flag array. Wave w owns k-slice [128w,128w+128): loads 8 chunks
// (64 KB/WG/step, half of before), 96 MFMAs. Handshake (per system):
// single polling wave, all-32 flags >= step covers data-ready AND
// write-safety (publish of s-1 implies consumption of s-1's input buffer).
__global__ __launch_bounds__(256, 1) void lstm_recur(
    const f16_t* __restrict__ xp, const __bf16* __restrict__ whh,
    const __bf16* __restrict__ whl, const float* __restrict__ sent,
    float* __restrict__ out, unsigned int* __restrict__ hpk,
    unsigned int* __restrict__ flags)
{
  int bid = blockIdx.x;
  int dir = bid >> 6;
  int hb  = (bid >> 5) & 1;
  int jb  = bid & 31;
  int tid = threadIdx.x, w = tid >> 6, lane = tid & 63;
  int q = lane >> 4, jj = lane & 15;
  int ww = w & 1;              // local b-group (mi local)
  int rh = (w >> 1) * 2;       // r base for elementwise (2 per thread)
  const int cbase = ((jb >> 3) << 4) + ((jb >> 1) & 3);  // chunk base for this WG's cols

  // B fragments (step-invariant) -> registers. [g][kb], k = w*128+kb*32+q*8+i.
  bf16x8 bh_r[4][4], bl_r[4][4];
  {
    const __bf16* sh = whh + (size_t)dir * 2048 * NH;
    const __bf16* sl = whl + (size_t)dir * 2048 * NH;
#pragma unroll
    for (int g = 0; g < 4; ++g) {
      size_t nrow = (size_t)(g * NH + jb * 16 + jj) * NH + w * 128 + q * 8;
#pragma unroll
      for (int kb = 0; kb < 4; ++kb) {
        bh_r[g][kb] = *(const bf16x8*)(sh + nrow + kb * 32);
        bl_r[g][kb] = *(const bf16x8*)(sl + nrow + kb * 32);
      }
    }
  }

  __shared__ f32x4 pbuf[4][2][4][64];           // [src_wave][ml][g][lane], 32 KB
  __shared__ unsigned int stage[2][4][2][32];   // [ml][s][jj>>3][(b&15)*2+par], 2 KB

  float cst[2] = {0.f, 0.f};
  unsigned int* fl = flags + (dir * 2 + hb) * 32;
  const f16_t* xslab = xp + ((size_t)(dir * 32 + jb) * 512) * 4096;

  for (int step = 0; step < NS; ++step) {
    int t = dir ? (NS - 1 - step) : step;

    // xp + sentiment prefetch (independent of h -> overlaps the wait)
    float xg[4][2];  // [g][rr]
    float st[2];
    {
      const f16_t* xrow = xslab + (size_t)t * 4096;
#pragma unroll
      for (int rr = 0; rr < 2; ++rr) {
        int b = (2 * hb + ww) * 16 + q * 4 + rh + rr;
#pragma unroll
        for (int g = 0; g < 4; ++g)
          xg[g][rr] = (float)xrow[b * 64 + g * 16 + jj];
        st[rr] = sent[b * NS + t];
      }
    }

    // handshake: wave 0 polls own system's 32 flags (one 128 B line)
    if (step) {
      if (tid < 64) {
        unsigned v = 0;
        for (;;) {
          if (lane < 32)
            v = __hip_atomic_load(fl + lane, __ATOMIC_RELAXED, __HIP_MEMORY_SCOPE_AGENT);
          if (__all(lane >= 32 || v >= (unsigned)step)) break;
          __builtin_amdgcn_s_sleep(1);
        }
      }
      __syncthreads();
    }

    const unsigned long long* hrd =
        (const unsigned long long*)(hpk + (size_t)(dir * 2 + (step & 1)) * 32768);
    unsigned int* hwr = hpk + (size_t)(dir * 2 + ((step & 1) ^ 1)) * 32768;

    f32x4 acc[2][4] = {};  // [ml][g] k-partials for this wave's slice
    if (step) {
      bf16x8 Ah[2][4], Al[2][4];
      // wave's 8 chunks for its batch half: c = w*16 + (2hb+ml)*4 + kb
      const unsigned long long* hbp = hrd + ((size_t)(w * 16 + 8 * hb)) * 256 + lane;
#pragma unroll
      for (int kb = 0; kb < 4; ++kb)
        loadA16c(hbp + kb * 256, Ah[0][kb], Al[0][kb]);
#pragma unroll
      for (int ml = 0; ml < 2; ++ml) {
        if (ml == 0) {
#pragma unroll
          for (int kb = 0; kb < 4; ++kb)
            loadA16c(hbp + 1024 + kb * 256, Ah[1][kb], Al[1][kb]);
        }
#pragma unroll
        for (int kb = 0; kb < 4; ++kb)
#pragma unroll
          for (int g = 0; g < 4; ++g) {
            acc[ml][g] = __builtin_amdgcn_mfma_f32_16x16x32_bf16(Ah[ml][kb], bh_r[g][kb], acc[ml][g], 0, 0, 0);
            acc[ml][g] = __builtin_amdgcn_mfma_f32_16x16x32_bf16(Al[ml][kb], bh_r[g][kb], acc[ml][g], 0, 0, 0);
            acc[ml][g] = __builtin_amdgcn_mfma_f32_16x16x32_bf16(Ah[ml][kb], bl_r[g][kb], acc[ml][g], 0, 0, 0);
          }
      }
    }

    // cross-wave k-reduction through LDS (lane-indexed b128, conflict-free)
#pragma unroll
    for (int ml = 0; ml < 2; ++ml)
#pragma unroll
      for (int g = 0; g < 4; ++g) pbuf[w][ml][g][lane] = acc[ml][g];
    __syncthreads();
    f32x4 gates[4];
#pragma unroll
    for (int g = 0; g < 4; ++g) gates[g] = acc[ww][g];
#pragma unroll
    for (int w2 = 0; w2 < 4; ++w2)
      if (w2 != w)
#pragma unroll
        for (int g = 0; g < 4; ++g) gates[g] += pbuf[w2][ww][g][lane];

    // elementwise: thread owns (b = (2hb+ww)*16 + q*4 + rh+rr, jj), rr in {0,1}
#pragma unroll
    for (int rr = 0; rr < 2; ++rr) {
      int r = rh + rr;
      int b = (2 * hb + ww) * 16 + q * 4 + r;
      float it = fsig(gates[0][r] + xg[0][rr]) * st[rr];
      float ft = fsig(gates[1][r] + xg[1][rr]) * (1.f + st[rr]);
      float gt = ftanh(gates[2][r] + xg[2][rr]);
      float ot = fsig(gates[3][r] + xg[3][rr]);
      float cv = ft * cst[rr] + it * gt;
      cst[rr] = cv;
      float h = ot * ftanh(cv);
      out[((long)b * NS + t) * 1024 + dir * 512 + jb * 16 + jj] = h;
      __bf16 h_hi = (__bf16)h;
      __bf16 h_lo = (__bf16)(h - (float)h_hi);
      unsigned pk = ((unsigned)__builtin_bit_cast(unsigned short, h_hi) << 16)
                  | (unsigned)__builtin_bit_cast(unsigned short, h_lo);
      stage[ww][(jj >> 1) & 3][jj >> 3][((q * 4 + r) << 1) + (jj & 1)] = pk;
    }
    __syncthreads();

    // publish: 128 threads x 1 dwordx4 store (dense, full-line write-through)
    if (tid < 128) {
      int rid  = tid >> 3;        // 0..15
      int wpl  = rid >> 3;        // local mi
      int s    = (rid >> 1) & 3;  // u64 slot
      int hi3  = rid & 1;         // jj>>3 half
      int slot = tid & 7;         // 16 B within the 128 B run
      int mig  = 2 * hb + wpl;    // global mi (chunk index component)
      const unsigned int* sp = &stage[wpl][s][hi3][slot << 2];
      unsigned base = ((unsigned)(cbase + (mig << 2)) << 9) + ((unsigned)s << 7)
                    + ((unsigned)((jb * 2 + hi3) & 3) << 5) + ((unsigned)slot << 2);
      u32x4 v;
      v.x = sp[0]; v.y = sp[1]; v.z = sp[2]; v.w = sp[3];
      asm volatile("global_store_dwordx4 %0, %1, off sc0 sc1"
                   :: "v"((unsigned long long)(hwr + base)), "v"(v) : "memory");
    }

    // barrier drains vmcnt(0): publishes are at the coherent point; then flag.
    __syncthreads();
    if (tid == 0)
      __hip_atomic_store(fl + jb, (unsigned)(step + 1),
                         __ATOMIC_RELAXED, __HIP_MEMORY_SCOPE_AGENT);
  }
}

extern "C" void kernel_launch(void* const* d_in, const int* in_sizes, int n_in,
                              void* d_out, int out_size, void* d_ws, size_t ws_size,
                              hipStream_t stream) {
  const float* x    = (const float*)d_in[0];
  const float* sent = (const float*)d_in[1];
  const float* Wi_f = (const float*)d_in[2];
  const float* bi_f = (const float*)d_in[3];
  const float* Wh_f = (const float*)d_in[4];
  const float* bh_f = (const float*)d_in[5];
  const float* Wi_b = (const float*)d_in[6];
  const float* bi_b = (const float*)d_in[7];
  const float* Wh_b = (const float*)d_in[8];
  const float* bh_b = (const float*)d_in[9];

  char* ws = (char*)d_ws;
  __bf16*       wiT_h = (__bf16*)(ws + WS_WITH);
  __bf16*       wiT_l = (__bf16*)(ws + WS_WITL);
  __bf16*       whT_h = (__bf16*)(ws + WS_WHTH);
  __bf16*       whT_l = (__bf16*)(ws + WS_WHTL);
  f16_t*        xp    = (f16_t*)(ws + WS_XP);
  unsigned int* hpk   = (unsigned int*)(ws + WS_HPK);
  unsigned int* flags = (unsigned int*)(ws + WS_CNT);
  unsigned int* zr    = (unsigned int*)(ws + WS_HPK);  // hpk+flags contiguous

  prep_zero<<<dim3(513), dim3(256), 0, stream>>>(zr);
  transpose_cast<<<dim3(1536, 4), dim3(256), 0, stream>>>(
      Wi_f, Wh_f, Wi_b, Wh_b, wiT_h, wiT_l, whT_h, whT_l);
  gemm_xproj<<<dim3(4096, 2), dim3(256), 0, stream>>>(
      x, wiT_h, wiT_l, bi_f, bh_f, bi_b, bh_b, xp);
  lstm_recur<<<dim3(128), dim3(256), 0, stream>>>(
      xp, whT_h, whT_l, sent, (float*)d_out, hpk, flags);
}

// Round 5
// 2631.238 us; speedup vs baseline: 2.6430x; 1.9270x over previous
//
#include <hip/hip_runtime.h>

typedef __bf16   bf16x8 __attribute__((ext_vector_type(8)));
typedef float    f32x4  __attribute__((ext_vector_type(4)));
typedef unsigned int u32x4 __attribute__((ext_vector_type(4)));
typedef _Float16 f16_t;

#define NB 64
#define NS 512
#define NI 768
#define NH 512

// ---------------- workspace layout (bytes), total ~276.6 MB ----------------
// wiT_h: bf16 [2][2048][768]      @ 0           ( 6,291,456)
// wiT_l: bf16 [2][2048][768]      @ 6291456     ( 6,291,456)
// whT_h: bf16 [2][2048][512]      @ 12582912    ( 4,194,304)
// whT_l: bf16 [2][2048][512]      @ 16777216    ( 4,194,304)
// xp   : f16  [2][32][512][64][64] @ 20971520   (268,435,456)  (dir,jb,t,b,g*16+jj)
// hpk  : u32  [2dir][2par][64 chunks][512] @ 289406976 (524,288)
//        chunk c = w*16 + mi*4 + kb holds A-frag (b=mi*16+jj, k=w*128+kb*32+q*8+j)
//        u32 idx in chunk = (j>>1)*128 + (q*16+(b&15))*2 + (j&1)  (hi<<16|lo packed)
//        batch-split 4x: chunk group mi == batch quarter hb.
// flags: u32  [2dir][4hb][32]     @ 289931264   (1,024)  flag[jb] = published step+1
//        each 32-flag group is one 128 B line; 8 independent handshake systems.
#define WS_WITH  0L
#define WS_WITL  6291456L
#define WS_WHTH  12582912L
#define WS_WHTL  16777216L
#define WS_XP    20971520L
#define WS_HPK   289406976L
#define WS_CNT   289931264L

__device__ __forceinline__ float fsig(float x) {
  return __builtin_amdgcn_rcpf(1.f + __builtin_amdgcn_exp2f(-1.442695040888963f * x));
}
__device__ __forceinline__ float ftanh(float x) {
  return 1.f - 2.f * __builtin_amdgcn_rcpf(1.f + __builtin_amdgcn_exp2f(2.885390081777926f * x));
}

// split 8 consecutive LDS floats into hi/lo bf16x8 fragments
__device__ __forceinline__ void split8(const float* p, bf16x8& hi, bf16x8& lo) {
#pragma unroll
  for (int j = 0; j < 8; ++j) {
    float v = p[j];
    __bf16 h = (__bf16)v;
    hi[j] = h;
    lo[j] = (__bf16)(v - (float)h);
  }
}

// Chunked A-fragment load: p = chunk_base_u64 + lane. The 4 u64 loads have
// 8 B lane stride (fully coalesced, 512 B dense per instruction). u64 s holds
// packed u32 pair (j=2s, j=2s+1); unpack hi/lo bf16x8 with v_perm.
__device__ __forceinline__ void loadA16c(const unsigned long long* p, bf16x8& hi, bf16x8& lo) {
  unsigned long long q0 = __hip_atomic_load(p +   0, __ATOMIC_RELAXED, __HIP_MEMORY_SCOPE_AGENT);
  unsigned long long q1 = __hip_atomic_load(p +  64, __ATOMIC_RELAXED, __HIP_MEMORY_SCOPE_AGENT);
  unsigned long long q2 = __hip_atomic_load(p + 128, __ATOMIC_RELAXED, __HIP_MEMORY_SCOPE_AGENT);
  unsigned long long q3 = __hip_atomic_load(p + 192, __ATOMIC_RELAXED, __HIP_MEMORY_SCOPE_AGENT);
  unsigned a0 = (unsigned)q0, a1 = (unsigned)(q0 >> 32);
  unsigned a2 = (unsigned)q1, a3 = (unsigned)(q1 >> 32);
  unsigned a4 = (unsigned)q2, a5 = (unsigned)(q2 >> 32);
  unsigned a6 = (unsigned)q3, a7 = (unsigned)(q3 >> 32);
  union { unsigned u[4]; bf16x8 v; } H, L;
  H.u[0] = __builtin_amdgcn_perm(a1, a0, 0x07060302);
  H.u[1] = __builtin_amdgcn_perm(a3, a2, 0x07060302);
  H.u[2] = __builtin_amdgcn_perm(a5, a4, 0x07060302);
  H.u[3] = __builtin_amdgcn_perm(a7, a6, 0x07060302);
  L.u[0] = __builtin_amdgcn_perm(a1, a0, 0x05040100);
  L.u[1] = __builtin_amdgcn_perm(a3, a2, 0x05040100);
  L.u[2] = __builtin_amdgcn_perm(a5, a4, 0x05040100);
  L.u[3] = __builtin_amdgcn_perm(a7, a6, 0x05040100);
  hi = H.v; lo = L.v;
}

// ---------------- prep: zero hpk + flags ----------------
__global__ __launch_bounds__(256) void prep_zero(unsigned int* __restrict__ zr) {
  unsigned wi = blockIdx.x * 256u + threadIdx.x;
  if (wi < 131328u) zr[wi] = 0u;  // hpk (131072 words) + flags (256 words)
}

// ---------------- prep: transpose + split-cast Wi/Wh -> [N][K] bf16 hi+lo ----------------
__global__ __launch_bounds__(256) void transpose_cast(
    const float* __restrict__ Wi_f, const float* __restrict__ Wh_f,
    const float* __restrict__ Wi_b, const float* __restrict__ Wh_b,
    __bf16* __restrict__ wiT_h, __bf16* __restrict__ wiT_l,
    __bf16* __restrict__ whT_h, __bf16* __restrict__ whT_l)
{
  int mat = blockIdx.y;  // 0:Wi_f 1:Wh_f 2:Wi_b 3:Wh_b
  const float* src = (mat == 0) ? Wi_f : (mat == 1) ? Wh_f : (mat == 2) ? Wi_b : Wh_b;
  int K = (mat & 1) ? NH : NI;
  size_t doff = (mat >= 2) ? (size_t)2048 * K : 0;
  __bf16* dh = ((mat & 1) ? whT_h : wiT_h) + doff;
  __bf16* dl = ((mat & 1) ? whT_l : wiT_l) + doff;
  int ntk = K / 32;
  int t = blockIdx.x;
  if (t >= ntk * 64) return;
  int tk = t >> 6, tn = t & 63;
  __shared__ float tb[32][33];
  int tx = threadIdx.x & 31, ty = threadIdx.x >> 5;
#pragma unroll
  for (int i = 0; i < 4; ++i)
    tb[ty + i * 8][tx] = src[(size_t)(tk * 32 + ty + i * 8) * 2048 + tn * 32 + tx];
  __syncthreads();
#pragma unroll
  for (int i = 0; i < 4; ++i) {
    float v = tb[tx][ty + i * 8];
    __bf16 hi = (__bf16)v;
    size_t o = (size_t)(tn * 32 + ty + i * 8) * K + tk * 32 + tx;
    dh[o] = hi;
    dl[o] = (__bf16)(v - (float)hi);
  }
}

// ---------------- phase 1: xp = x @ Wi + (bi + bh), f16 out, 3-term split ----------------
// Output in recurrence-friendly layout: xp[dir][jb][t][b][g*16+jj].
__global__ __launch_bounds__(256) void gemm_xproj(
    const float* __restrict__ x,
    const __bf16* __restrict__ wih, const __bf16* __restrict__ wil,
    const float* __restrict__ bi_f, const float* __restrict__ bh_f,
    const float* __restrict__ bi_b, const float* __restrict__ bh_b,
    f16_t* __restrict__ xp)
{
  int dir = blockIdx.y;
  int tm = blockIdx.x >> 4, tn = blockIdx.x & 15;
  const float*  Af = x + (size_t)tm * 128 * NI;
  const __bf16* Bh = wih + (size_t)dir * 2048 * NI + (size_t)tn * 128 * NI;
  const __bf16* Bl = wil + (size_t)dir * 2048 * NI + (size_t)tn * 128 * NI;
  const float* bi = dir ? bi_b : bi_f;
  const float* bh = dir ? bh_b : bh_f;

  __shared__ float  sA[128 * 32];
  __shared__ __bf16 sBh[128 * 32];
  __shared__ __bf16 sBl[128 * 32];
  int tid = threadIdx.x, w = tid >> 6, lane = tid & 63;
  int wm = w >> 1, wn = w & 1;
  int q = lane >> 4, m16 = lane & 15;

  f32x4 acc[4][4] = {};
  for (int kb = 0; kb < NI / 32; ++kb) {
#pragma unroll
    for (int i = 0; i < 4; ++i) {
      int ch = tid + i * 256;
      int r = ch >> 3, c = ch & 7;
      __builtin_amdgcn_global_load_lds(
          (__attribute__((address_space(1))) void*)(Af + (size_t)r * NI + kb * 32 + c * 4),
          (__attribute__((address_space(3))) void*)(sA + ch * 4), 16, 0, 0);
    }
#pragma unroll
    for (int i = 0; i < 2; ++i) {
      int ch = tid + i * 256;
      int r = ch >> 2, c = ch & 3;
      size_t go = (size_t)r * NI + kb * 32 + c * 8;
      __builtin_amdgcn_global_load_lds(
          (__attribute__((address_space(1))) void*)(Bh + go),
          (__attribute__((address_space(3))) void*)(sBh + ch * 8), 16, 0, 0);
      __builtin_amdgcn_global_load_lds(
          (__attribute__((address_space(1))) void*)(Bl + go),
          (__attribute__((address_space(3))) void*)(sBl + ch * 8), 16, 0, 0);
    }
    __syncthreads();
    bf16x8 afh[4], afl[4], bfh[4], bfl[4];
#pragma unroll
    for (int i = 0; i < 4; ++i) {
      split8(sA + (wm * 64 + i * 16 + m16) * 32 + q * 8, afh[i], afl[i]);
      int bo = (wn * 64 + i * 16 + m16) * 32 + q * 8;
      bfh[i] = *(const bf16x8*)(sBh + bo);
      bfl[i] = *(const bf16x8*)(sBl + bo);
    }
#pragma unroll
    for (int mi = 0; mi < 4; ++mi)
#pragma unroll
      for (int ni = 0; ni < 4; ++ni) {
        acc[mi][ni] = __builtin_amdgcn_mfma_f32_16x16x32_bf16(afh[mi], bfh[ni], acc[mi][ni], 0, 0, 0);
        acc[mi][ni] = __builtin_amdgcn_mfma_f32_16x16x32_bf16(afl[mi], bfh[ni], acc[mi][ni], 0, 0, 0);
        acc[mi][ni] = __builtin_amdgcn_mfma_f32_16x16x32_bf16(afh[mi], bfl[ni], acc[mi][ni], 0, 0, 0);
      }
    __syncthreads();
  }
#pragma unroll
  for (int ni = 0; ni < 4; ++ni) {
    int n = tn * 128 + wn * 64 + ni * 16 + m16;
    int g = n >> 9, jbx = (n >> 4) & 31, jjx = n & 15;
    float bias = bi[n] + bh[n];
    size_t nbase = ((size_t)(dir * 32 + jbx) * 512) * 4096 + g * 16 + jjx;
#pragma unroll
    for (int mi = 0; mi < 4; ++mi) {
#pragma unroll
      for (int r = 0; r < 4; ++r) {
        int m = tm * 128 + wm * 64 + mi * 16 + q * 4 + r;
        int b = m >> 9, t = m & 511;
        xp[nbase + (size_t)t * 4096 + b * 64] = (f16_t)(acc[mi][ni][r] + bias);
      }
    }
  }
}

// ---------------- phase 2: recurrence, batch-split 4x ----------------
// 256 WGs (2 dir x 4 batch-quarter x 32 jb), 256 threads, 1 WG/CU (full GPU).
// WG (dir,hb,jb) owns h cols [16jb,16jb+16) for batches [16hb,16hb+16)
// (b-group mi == hb). Chunk map: chunk group mi <-> quarter hb, so each
// (dir,hb) is an INDEPENDENT 32-WG exchange system with its own 1-line flag
// array (8 systems total). Wave w owns k-slice [128w,128w+128): loads 4
// chunks (32 KB/WG/step), 48 MFMAs. Elementwise: 1 (b,jj) value per thread
// (b = hb*16 + q*4 + w). Publish: 64 threads x dwordx4 = the WG's half-chunk
// (q_c in {2(jb&1), 2(jb&1)+1} of chunk cbase + hb*4), full-line dense.
// Handshake: single polling wave; all-32 flags >= step covers data-ready AND
// write-safety (publish of s-1 implies consumption of s-2's buffer, which is
// the parity slot being overwritten at step s).
__global__ __launch_bounds__(256, 1) void lstm_recur(
    const f16_t* __restrict__ xp, const __bf16* __restrict__ whh,
    const __bf16* __restrict__ whl, const float* __restrict__ sent,
    float* __restrict__ out, unsigned int* __restrict__ hpk,
    unsigned int* __restrict__ flags)
{
  int bid = blockIdx.x;
  int dir = bid >> 7;
  int hb  = (bid >> 5) & 3;
  int jb  = bid & 31;
  int tid = threadIdx.x, w = tid >> 6, lane = tid & 63;
  int q = lane >> 4, jj = lane & 15;
  const int cbase = ((jb >> 3) << 4) + ((jb >> 1) & 3);  // w_c*16 + kb_c for this WG's cols

  // B fragments (step-invariant) -> registers. [g][kb], k = w*128+kb*32+q*8+i.
  bf16x8 bh_r[4][4], bl_r[4][4];
  {
    const __bf16* sh = whh + (size_t)dir * 2048 * NH;
    const __bf16* sl = whl + (size_t)dir * 2048 * NH;
#pragma unroll
    for (int g = 0; g < 4; ++g) {
      size_t nrow = (size_t)(g * NH + jb * 16 + jj) * NH + w * 128 + q * 8;
#pragma unroll
      for (int kb = 0; kb < 4; ++kb) {
        bh_r[g][kb] = *(const bf16x8*)(sh + nrow + kb * 32);
        bl_r[g][kb] = *(const bf16x8*)(sl + nrow + kb * 32);
      }
    }
  }

  __shared__ f32x4 pbuf[4][4][64];              // [src_wave][g][lane], 16 KB
  __shared__ unsigned int stage[4][2][32];      // [s][jj>>3][(b&15)*2+par], 1 KB

  float cst = 0.f;
  unsigned int* fl = flags + (dir * 4 + hb) * 32;
  const f16_t* xslab = xp + ((size_t)(dir * 32 + jb) * 512) * 4096;

  for (int step = 0; step < NS; ++step) {
    int t = dir ? (NS - 1 - step) : step;

    // xp + sentiment prefetch (independent of h -> overlaps the wait)
    float xg[4];
    float st;
    int b = hb * 16 + q * 4 + w;
    {
      const f16_t* xrow = xslab + (size_t)t * 4096;
#pragma unroll
      for (int g = 0; g < 4; ++g)
        xg[g] = (float)xrow[b * 64 + g * 16 + jj];
      st = sent[b * NS + t];
    }

    // handshake: wave 0 polls own system's 32 flags (one 128 B line)
    if (step) {
      if (tid < 64) {
        unsigned v = 0;
        for (;;) {
          if (lane < 32)
            v = __hip_atomic_load(fl + lane, __ATOMIC_RELAXED, __HIP_MEMORY_SCOPE_AGENT);
          if (__all(lane >= 32 || v >= (unsigned)step)) break;
          __builtin_amdgcn_s_sleep(1);
        }
      }
      __syncthreads();
    }

    const unsigned long long* hrd =
        (const unsigned long long*)(hpk + (size_t)(dir * 2 + (step & 1)) * 32768);
    unsigned int* hwr = hpk + (size_t)(dir * 2 + ((step & 1) ^ 1)) * 32768;

    f32x4 acc[4] = {};  // [g] k-partials for this wave's slice, b-group hb
    if (step) {
      bf16x8 Ah[4], Al[4];
      // wave's 4 chunks: c = w*16 + hb*4 + kb
      const unsigned long long* hbp = hrd + ((size_t)(w * 16 + hb * 4)) * 256 + lane;
#pragma unroll
      for (int kb = 0; kb < 4; ++kb)
        loadA16c(hbp + kb * 256, Ah[kb], Al[kb]);
#pragma unroll
      for (int kb = 0; kb < 4; ++kb)
#pragma unroll
        for (int g = 0; g < 4; ++g) {
          acc[g] = __builtin_amdgcn_mfma_f32_16x16x32_bf16(Ah[kb], bh_r[g][kb], acc[g], 0, 0, 0);
          acc[g] = __builtin_amdgcn_mfma_f32_16x16x32_bf16(Al[kb], bh_r[g][kb], acc[g], 0, 0, 0);
          acc[g] = __builtin_amdgcn_mfma_f32_16x16x32_bf16(Ah[kb], bl_r[g][kb], acc[g], 0, 0, 0);
        }
    }

    // cross-wave k-reduction through LDS (lane-indexed b128, conflict-free)
#pragma unroll
    for (int g = 0; g < 4; ++g) pbuf[w][g][lane] = acc[g];
    __syncthreads();
    f32x4 gates[4];
#pragma unroll
    for (int g = 0; g < 4; ++g) gates[g] = acc[g];
#pragma unroll
    for (int w2 = 0; w2 < 4; ++w2)
      if (w2 != w)
#pragma unroll
        for (int g = 0; g < 4; ++g) gates[g] += pbuf[w2][g][lane];

    // extract this thread's row r = w (wave-uniform, compile-time indices)
    float g0, g1, g2, g3;
#pragma unroll
    for (int r = 0; r < 4; ++r)
      if (r == w) { g0 = gates[0][r]; g1 = gates[1][r]; g2 = gates[2][r]; g3 = gates[3][r]; }

    // elementwise: thread owns (b = hb*16 + q*4 + w, jj)
    {
      float it = fsig(g0 + xg[0]) * st;
      float ft = fsig(g1 + xg[1]) * (1.f + st);
      float gt = ftanh(g2 + xg[2]);
      float ot = fsig(g3 + xg[3]);
      float cv = ft * cst + it * gt;
      cst = cv;
      float h = ot * ftanh(cv);
      out[((long)b * NS + t) * 1024 + dir * 512 + jb * 16 + jj] = h;
      __bf16 h_hi = (__bf16)h;
      __bf16 h_lo = (__bf16)(h - (float)h_hi);
      unsigned pk = ((unsigned)__builtin_bit_cast(unsigned short, h_hi) << 16)
                  | (unsigned)__builtin_bit_cast(unsigned short, h_lo);
      stage[(jj >> 1) & 3][jj >> 3][((q * 4 + w) << 1) + (jj & 1)] = pk;
    }
    __syncthreads();

    // publish: 64 threads x 1 dwordx4 store (8 full 128 B lines, dense)
    if (tid < 64) {
      int rid  = tid >> 3;        // 0..7
      int s    = (rid >> 1) & 3;  // u64 slot
      int hi3  = rid & 1;         // jj>>3 half
      int slot = tid & 7;         // 16 B within the 128 B run
      const unsigned int* sp = &stage[s][hi3][slot << 2];
      unsigned base = ((unsigned)(cbase + (hb << 2)) << 9) + ((unsigned)s << 7)
                    + ((unsigned)((jb * 2 + hi3) & 3) << 5) + ((unsigned)slot << 2);
      u32x4 v;
      v.x = sp[0]; v.y = sp[1]; v.z = sp[2]; v.w = sp[3];
      asm volatile("global_store_dwordx4 %0, %1, off sc0 sc1"
                   :: "v"((unsigned long long)(hwr + base)), "v"(v) : "memory");
    }

    // barrier drains vmcnt(0): publishes are at the coherent point; then flag.
    __syncthreads();
    if (tid == 0)
      __hip_atomic_store(fl + jb, (unsigned)(step + 1),
                         __ATOMIC_RELAXED, __HIP_MEMORY_SCOPE_AGENT);
  }
}

extern "C" void kernel_launch(void* const* d_in, const int* in_sizes, int n_in,
                              void* d_out, int out_size, void* d_ws, size_t ws_size,
                              hipStream_t stream) {
  const float* x    = (const float*)d_in[0];
  const float* sent = (const float*)d_in[1];
  const float* Wi_f = (const float*)d_in[2];
  const float* bi_f = (const float*)d_in[3];
  const float* Wh_f = (const float*)d_in[4];
  const float* bh_f = (const float*)d_in[5];
  const float* Wi_b = (const float*)d_in[6];
  const float* bi_b = (const float*)d_in[7];
  const float* Wh_b = (const float*)d_in[8];
  const float* bh_b = (const float*)d_in[9];

  char* ws = (char*)d_ws;
  __bf16*       wiT_h = (__bf16*)(ws + WS_WITH);
  __bf16*       wiT_l = (__bf16*)(ws + WS_WITL);
  __bf16*       whT_h = (__bf16*)(ws + WS_WHTH);
  __bf16*       whT_l = (__bf16*)(ws + WS_WHTL);
  f16_t*        xp    = (f16_t*)(ws + WS_XP);
  unsigned int* hpk   = (unsigned int*)(ws + WS_HPK);
  unsigned int* flags = (unsigned int*)(ws + WS_CNT);
  unsigned int* zr    = (unsigned int*)(ws + WS_HPK);  // hpk+flags contiguous

  prep_zero<<<dim3(513), dim3(256), 0, stream>>>(zr);
  transpose_cast<<<dim3(1536, 4), dim3(256), 0, stream>>>(
      Wi_f, Wh_f, Wi_b, Wh_b, wiT_h, wiT_l, whT_h, whT_l);
  gemm_xproj<<<dim3(4096, 2), dim3(256), 0, stream>>>(
      x, wiT_h, wiT_l, bi_f, bh_f, bi_b, bh_b, xp);
  lstm_recur<<<dim3(256), dim3(256), 0, stream>>>(
      xp, whT_h, whT_l, sent, (float*)d_out, hpk, flags);
}